// Round 3
// baseline (988.759 us; speedup 1.0000x reference)
//
#include <hip/hip_runtime.h>
#include <stdint.h>
#include <stddef.h>

// Problem constants (fixed by the reference)
#define M_ROWS 32768      // B*N = 16*2048
#define N_CODES 8192
#define K_DIM 512
#define BM 128
#define BN 128
#define BK 64
#define KITERS (K_DIM / BK)     // 8
#define CAND_CAP (3u*1024u*1024u)
#define LCAP 512u               // per-block LDS candidate slab
#define TAU2 2.0f               // admission/prune margin for bf16 approx dists (~14 sigma)
#define NLOSSBIN 128

// Output layout (floats): z_q [0,16777216), codes [16777216,16809984), loss, perp
#define OFF_CODES 16777216
#define OFF_LOSS  (16777216 + 32768)
#define OFF_PERP  (16777216 + 32768 + 1)

using short8  = __attribute__((ext_vector_type(8))) short;
using ushort8 = __attribute__((ext_vector_type(8))) unsigned short;
using f32x4   = __attribute__((ext_vector_type(4))) float;

typedef unsigned short u16;
typedef unsigned int   u32;
typedef unsigned long long u64;

// ---- orderable-uint encoding of float (monotone: uint min == float min) ----
__device__ __forceinline__ u32 ford(float f) {
    u32 u = __float_as_uint(f);
    return (u & 0x80000000u) ? ~u : (u | 0x80000000u);
}
__device__ __forceinline__ float fordinv(u32 u) {
    u32 v = (u & 0x80000000u) ? (u & 0x7FFFFFFFu) : ~u;
    return __uint_as_float(v);
}
// fp32 -> bf16 (RNE)
__device__ __forceinline__ u16 f2bf(float f) {
    u32 u = __float_as_uint(f);
    u = u + 0x7FFFu + ((u >> 16) & 1u);
    return (u16)(u >> 16);
}

// async global->LDS, 16B per lane; LDS dest = wave-uniform base + lane*16
__device__ __forceinline__ void ldg_to_lds16(const u16* g, u16* l) {
    __builtin_amdgcn_global_load_lds((__attribute__((address_space(1))) void*)(g),
                                     (__attribute__((address_space(3))) void*)(l),
                                     16, 0, 0);
}

// ---------------- init scratch state ----------------
__global__ void k_init(u32* rowMin, u64* rowBest, u32* counts, u32* candCnt,
                       float* lossPart) {
    int i = blockIdx.x * blockDim.x + threadIdx.x;
    if (i < M_ROWS) { rowMin[i] = 0xFFFFFFFFu; rowBest[i] = ~0ull; }
    if (i < N_CODES) counts[i] = 0u;
    if (i < NLOSSBIN) lossPart[i] = 0.0f;
    if (i == 0) *candCnt = 0u;
}

// ------------- fp32 -> bf16 convert + row squared norms -------------
__global__ void k_convert(const float* __restrict__ src, u16* __restrict__ dst,
                          float* __restrict__ nrm2, int nrows) {
    int row  = blockIdx.x * 4 + (threadIdx.x >> 6);
    int lane = threadIdx.x & 63;
    if (row >= nrows) return;
    const float* p = src + (size_t)row * K_DIM + lane * 8;
    float4 a = *(const float4*)p;
    float4 b = *(const float4*)(p + 4);
    ushort8 v;
    v[0]=f2bf(a.x); v[1]=f2bf(a.y); v[2]=f2bf(a.z); v[3]=f2bf(a.w);
    v[4]=f2bf(b.x); v[5]=f2bf(b.y); v[6]=f2bf(b.z); v[7]=f2bf(b.w);
    *(ushort8*)(dst + (size_t)row * K_DIM + lane * 8) = v;
    float ss = a.x*a.x + a.y*a.y + a.z*a.z + a.w*a.w
             + b.x*b.x + b.y*b.y + b.z*b.z + b.w*b.w;
    #pragma unroll
    for (int s = 32; s; s >>= 1) ss += __shfl_xor(ss, s);
    if (lane == 0) nrm2[row] = ss;
}

// ---------------- main bf16 GEMM + fused min/candidate epilogue ----------------
// s[m,n] = en2[n] - 2 * sum_k zb[m,k]*eb[n,k]  (row-wise argmin target)
// A-operand: DIRECT global->register loads (thread-private; not drained by the
//   LDS barrier beyond the shared vmcnt). Lane layout: row R = wm+t*16+(lane&15),
//   k = q*8 (q=lane>>4) -> lanes {q=0..3} of one R cover a 64B row segment.
// B-operand: global_load_lds into XOR-swizzled LDS (block (R,g) at slot
//   R*8 + (g^(R&7))) -> ds_read_b128 frags 2-way (free), staging lane-linear.
// Candidates aggregated in LDS slab, ONE global atomicAdd per block.
__global__ __launch_bounds__(256, 3)
void k_gemm(const u16* __restrict__ zb, const u16* __restrict__ eb,
            const float* __restrict__ en2, u32* __restrict__ rowMin,
            u32* __restrict__ candCnt, u64* __restrict__ cand) {
    __shared__ __align__(16) u16 Bs[BN * BK];
    __shared__ float en2s[BN];
    __shared__ u32 threshL[BM];
    __shared__ u64 candBuf[LCAP];
    __shared__ u32 ldsCnt, ldsBase;

    const int tid  = threadIdx.x;
    const int lane = tid & 63;
    const int wave = tid >> 6;
    const int rowTile = blockIdx.x * BM;
    const int nTile   = blockIdx.y * BN;
    const int wm = (wave >> 1) * 64;   // wave's row quadrant
    const int wn = (wave & 1) * 64;    // wave's col quadrant
    const int q  = lane >> 4;

    if (tid < BN) { en2s[tid] = en2[nTile + tid]; threshL[tid] = 0xFFFFFFFFu; }
    if (tid == 0) ldsCnt = 0u;

    // B staging: wave w stages issues i = w*4+t; issue i covers Bs rows
    // [i*8, i*8+8); lane l -> row i*8+(l>>3), k-block g=(l&7)^((l>>3)&7).
    const int srow = (lane >> 3);
    const int sg   = (lane & 7) ^ ((lane >> 3) & 7);
    const u16* gB[4]; u16* lB[4];
    #pragma unroll
    for (int t = 0; t < 4; t++) {
        int i = wave * 4 + t;
        gB[t] = eb + (size_t)(nTile + i * 8 + srow) * K_DIM + sg * 8;
        lB[t] = Bs + i * 512;
    }

    // A direct-load bases: lane reads A[R][q*8 + j], R = wm + t*16 + (lane&15)
    const u16* pa[4];
    #pragma unroll
    for (int t = 0; t < 4; t++)
        pa[t] = zb + (size_t)(rowTile + wm + t * 16 + (lane & 15)) * K_DIM + q * 8;

    // B fragment read byte offsets (k-half 0); half 1 = offset ^ 64
    int boff[4];
    #pragma unroll
    for (int t = 0; t < 4; t++) {
        int Rn = wn + t * 16 + (lane & 15);
        boff[t] = (Rn * 8 + (q ^ (Rn & 7))) * 16;
    }

    f32x4 acc[4][4] = {};

    for (int kk = 0; kk < KITERS; kk++) {
        const int ko = kk * BK;
        #pragma unroll
        for (int t = 0; t < 4; t++)
            ldg_to_lds16(gB[t] + ko, lB[t]);
        __syncthreads();
        short8 af[4], bf_[4];
        // k-half 0
        #pragma unroll
        for (int t = 0; t < 4; t++) {
            af[t]  = *(const short8*)(pa[t] + ko);
            bf_[t] = *(const short8*)((const char*)Bs + boff[t]);
        }
        #pragma unroll
        for (int i = 0; i < 4; i++)
            #pragma unroll
            for (int j = 0; j < 4; j++)
                acc[i][j] = __builtin_amdgcn_mfma_f32_16x16x32_bf16(af[i], bf_[j], acc[i][j], 0, 0, 0);
        // k-half 1
        #pragma unroll
        for (int t = 0; t < 4; t++) {
            af[t]  = *(const short8*)(pa[t] + ko + 32);
            bf_[t] = *(const short8*)((const char*)Bs + (boff[t] ^ 64));
        }
        #pragma unroll
        for (int i = 0; i < 4; i++)
            #pragma unroll
            for (int j = 0; j < 4; j++)
                acc[i][j] = __builtin_amdgcn_mfma_f32_16x16x32_bf16(af[i], bf_[j], acc[i][j], 0, 0, 0);
        __syncthreads();
    }

    // ---- epilogue: s = en2 - 2*C ; per-row tile min ; candidate capture ----
    float e2v[4];
    #pragma unroll
    for (int j = 0; j < 4; j++) e2v[j] = en2s[wn + j * 16 + (lane & 15)];
    #pragma unroll
    for (int i = 0; i < 4; i++)
        #pragma unroll
        for (int j = 0; j < 4; j++)
            #pragma unroll
            for (int r = 0; r < 4; r++)
                acc[i][j][r] = e2v[j] - 2.0f * acc[i][j][r];

    float rm[4][4];
    #pragma unroll
    for (int i = 0; i < 4; i++)
        #pragma unroll
        for (int r = 0; r < 4; r++)
            rm[i][r] = fminf(fminf(acc[i][0][r], acc[i][1][r]),
                             fminf(acc[i][2][r], acc[i][3][r]));
    #pragma unroll
    for (int d = 1; d < 16; d <<= 1)
        #pragma unroll
        for (int i = 0; i < 4; i++)
            #pragma unroll
            for (int r = 0; r < 4; r++)
                rm[i][r] = fminf(rm[i][r], __shfl_xor(rm[i][r], d));

    if ((lane & 15) == 0) {
        #pragma unroll
        for (int i = 0; i < 4; i++)
            #pragma unroll
            for (int r = 0; r < 4; r++) {
                int lrow = wm + i * 16 + (lane >> 4) * 4 + r;
                u32 o = ford(rm[i][r]);
                atomicMin(&threshL[lrow], o);
                u32 old = atomicMin(&rowMin[rowTile + lrow], o);  // tightens via earlier tiles
                atomicMin(&threshL[lrow], old);
            }
    }
    __syncthreads();

    #pragma unroll
    for (int i = 0; i < 4; i++) {
        #pragma unroll
        for (int r = 0; r < 4; r++) {
            int lrow = wm + i * 16 + (lane >> 4) * 4 + r;
            float th = fordinv(threshL[lrow]) + TAU2;
            #pragma unroll
            for (int j = 0; j < 4; j++) {
                float sv = acc[i][j][r];
                if (sv <= th) {
                    u32 code = (u32)(nTile + wn + j * 16 + (lane & 15));
                    u64 pk = ((u64)ford(sv) << 32) |
                             (u64)(((u32)(rowTile + lrow) << 13) | code);
                    u32 idx = atomicAdd(&ldsCnt, 1u);       // LDS atomic: cheap
                    if (idx < LCAP) candBuf[idx] = pk;
                    else { u32 g = atomicAdd(candCnt, 1u);  // rare overflow path
                           if (g < CAND_CAP) cand[g] = pk; }
                }
            }
        }
    }
    __syncthreads();
    if (tid == 0) {
        u32 n = ldsCnt < LCAP ? ldsCnt : LCAP;
        ldsBase = atomicAdd(candCnt, n);                    // ONE global atomic per block
    }
    __syncthreads();
    u32 n = ldsCnt < LCAP ? ldsCnt : LCAP;
    for (u32 k2 = tid; k2 < n; k2 += 256) {
        u32 g = ldsBase + k2;
        if (g < CAND_CAP) cand[g] = candBuf[k2];
    }
}

// ---------------- fp32 exact refine of pruned candidates ----------------
__global__ void k_refine(const float* __restrict__ z, const float* __restrict__ emb,
                         const float* __restrict__ en2, const u32* __restrict__ candCnt,
                         const u64* __restrict__ cand, const u32* __restrict__ rowMin,
                         u64* __restrict__ rowBest) {
    u32 cnt = *candCnt; if (cnt > CAND_CAP) cnt = CAND_CAP;
    int gt = blockIdx.x * blockDim.x + threadIdx.x;
    u32 wid = (u32)(gt >> 6);
    int lane = gt & 63;
    u32 nw = (u32)((gridDim.x * blockDim.x) >> 6);
    for (u32 ci = wid; ci < cnt; ci += nw) {
        u64 pk = cand[ci];
        u32 rc = (u32)pk;
        u32 row = rc >> 13, code = rc & (N_CODES - 1);
        float ad = fordinv((u32)(pk >> 32));
        float gm = fordinv(rowMin[row]);
        if (ad > gm + TAU2) continue;   // pruned: can't be the true argmin
        const float4* zp = (const float4*)(z + (size_t)row * K_DIM) + lane * 2;
        const float4* ep = (const float4*)(emb + (size_t)code * K_DIM) + lane * 2;
        float4 a0 = zp[0], a1 = zp[1], b0 = ep[0], b1 = ep[1];
        float d = a0.x*b0.x + a0.y*b0.y + a0.z*b0.z + a0.w*b0.w
                + a1.x*b1.x + a1.y*b1.y + a1.z*b1.z + a1.w*b1.w;
        #pragma unroll
        for (int s = 32; s; s >>= 1) d += __shfl_xor(d, s);
        if (lane == 0) {
            float sv = en2[code] - 2.0f * d;
            u64 bk = ((u64)ford(sv) << 32) | (u64)code;
            atomicMin(rowBest + row, bk);
        }
    }
}

// ------- outputs: z_q gather, codes, counts, fused loss partials -------
__global__ void k_output(const u64* __restrict__ rowBest, const float* __restrict__ emb,
                         const float* __restrict__ zn2, float* __restrict__ out,
                         u32* __restrict__ counts, float* __restrict__ lossPart) {
    int row = blockIdx.x;
    u64 pk = rowBest[row];
    u32 code = (u32)(pk & 0xFFFFFFFFull);
    int t = threadIdx.x;  // 128 threads, 4 floats each
    float4 v = ((const float4*)(emb + (size_t)code * K_DIM))[t];
    ((float4*)(out + (size_t)row * K_DIM))[t] = v;
    if (t == 0) {
        out[OFF_CODES + row] = (float)code;
        atomicAdd(&counts[code], 1u);
        // ||z - e_c||^2 = zn2[row] + (en2[c] - 2 z.e_c) = zn2 + best s
        float d2 = zn2[row] + fordinv((u32)(pk >> 32));
        atomicAdd(&lossPart[row & (NLOSSBIN - 1)], d2);
    }
}

// ---------------- loss + perplexity (tiny now) ----------------
__global__ void k_final(const float* __restrict__ lossPart,
                        const u32* __restrict__ counts, float* __restrict__ out) {
    __shared__ float red[256];
    int t = threadIdx.x;
    float s1 = (t < NLOSSBIN) ? lossPart[t] : 0.0f;
    red[t] = s1; __syncthreads();
    for (int w = 128; w; w >>= 1) { if (t < w) red[t] += red[t + w]; __syncthreads(); }
    float lossSum = red[0];
    __syncthreads();
    float s2 = 0.f;
    for (int c = t; c < N_CODES; c += 256) {
        float p = (float)counts[c] * (1.0f / (float)M_ROWS);
        s2 += p * logf(p + 1e-10f);
    }
    red[t] = s2; __syncthreads();
    for (int w = 128; w; w >>= 1) { if (t < w) red[t] += red[t + w]; __syncthreads(); }
    if (t == 0) {
        out[OFF_LOSS] = 0.25f * lossSum / ((float)M_ROWS * (float)K_DIM);
        out[OFF_PERP] = expf(-red[0]);
    }
}

// ---------------- workspace layout (bytes) ----------------
#define WS_ZB      ((size_t)0)                       // 32768*512*2  = 33554432
#define WS_EB      ((size_t)33554432)                // 8192*512*2   = 8388608
#define WS_EN2     ((size_t)41943040)                // 8192*4
#define WS_ZN2     ((size_t)41975808)                // 32768*4
#define WS_ROWMIN  ((size_t)42106880)                // 32768*4
#define WS_ROWBEST ((size_t)42237952)                // 32768*8
#define WS_COUNTS  ((size_t)42500096)                // 8192*4
#define WS_CANDCNT ((size_t)42532864)                // 256
#define WS_LOSSP   ((size_t)42533120)                // 128*4 = 512
#define WS_CAND    ((size_t)42533632)                // 3M*8 = 25165824 -> total ~67.7MB

extern "C" void kernel_launch(void* const* d_in, const int* in_sizes, int n_in,
                              void* d_out, int out_size, void* d_ws, size_t ws_size,
                              hipStream_t stream) {
    const float* z   = (const float*)d_in[0];
    const float* emb = (const float*)d_in[1];
    float* out = (float*)d_out;
    char* ws = (char*)d_ws;

    u16*  zb      = (u16*)(ws + WS_ZB);
    u16*  eb      = (u16*)(ws + WS_EB);
    float* en2    = (float*)(ws + WS_EN2);
    float* zn2    = (float*)(ws + WS_ZN2);
    u32*  rowMin  = (u32*)(ws + WS_ROWMIN);
    u64*  rowBest = (u64*)(ws + WS_ROWBEST);
    u32*  counts  = (u32*)(ws + WS_COUNTS);
    u32*  candCnt = (u32*)(ws + WS_CANDCNT);
    float* lossP  = (float*)(ws + WS_LOSSP);
    u64*  cand    = (u64*)(ws + WS_CAND);

    k_init<<<dim3(M_ROWS / 256), dim3(256), 0, stream>>>(rowMin, rowBest, counts, candCnt, lossP);
    k_convert<<<dim3(M_ROWS / 4), dim3(256), 0, stream>>>(z, zb, zn2, M_ROWS);
    k_convert<<<dim3(N_CODES / 4), dim3(256), 0, stream>>>(emb, eb, en2, N_CODES);
    k_gemm<<<dim3(M_ROWS / BM, N_CODES / BN), dim3(256), 0, stream>>>(zb, eb, en2, rowMin, candCnt, cand);
    k_refine<<<dim3(1024), dim3(256), 0, stream>>>(z, emb, en2, candCnt, cand, rowMin, rowBest);
    k_output<<<dim3(M_ROWS), dim3(128), 0, stream>>>(rowBest, emb, zn2, out, counts, lossP);
    k_final<<<dim3(1), dim3(256), 0, stream>>>(lossP, counts, out);
}

// Round 4
// 762.332 us; speedup vs baseline: 1.2970x; 1.2970x over previous
//
#include <hip/hip_runtime.h>
#include <stdint.h>
#include <stddef.h>

// Problem constants (fixed by the reference)
#define M_ROWS 32768      // B*N = 16*2048
#define N_CODES 8192
#define K_DIM 512
#define BM 128
#define BN 128
#define BK 64
#define KITERS (K_DIM / BK)     // 8
#define CAND_CAP (3u*1024u*1024u)
#define LCAP 512u               // per-block LDS candidate slab
#define TAU2 28.0f              // admission/prune margin for fp8 approx dists (sigma~2.8, ~7x extreme stat)
#define NLOSSBIN 128

// Output layout (floats): z_q [0,16777216), codes [16777216,16809984), loss, perp
#define OFF_CODES 16777216
#define OFF_LOSS  (16777216 + 32768)
#define OFF_PERP  (16777216 + 32768 + 1)

using f32x4   = __attribute__((ext_vector_type(4))) float;
using long2_t = __attribute__((ext_vector_type(2))) long;

typedef unsigned char  u8;
typedef unsigned short u16;
typedef unsigned int   u32;
typedef unsigned long long u64;

// ---- orderable-uint encoding of float (monotone: uint min == float min) ----
__device__ __forceinline__ u32 ford(float f) {
    u32 u = __float_as_uint(f);
    return (u & 0x80000000u) ? ~u : (u | 0x80000000u);
}
__device__ __forceinline__ float fordinv(u32 u) {
    u32 v = (u & 0x80000000u) ? (u & 0x7FFFFFFFu) : ~u;
    return __uint_as_float(v);
}

// fp32 -> OCP e4m3fn (RNE; flush |x| < 2^-6 to 0 — fine for screening)
__device__ __forceinline__ u8 f2e4m3(float f) {
    u32 u = __float_as_uint(f);
    u32 s = (u >> 24) & 0x80u;
    float a = fabsf(f);
    if (a < 0.015625f) return (u8)s;
    u32 au = u & 0x7FFFFFFFu;
    u32 r = au + 0x7FFFFu + ((au >> 20) & 1u);   // RNE to 3 mantissa bits
    int e = (int)(r >> 23) - 127;                // inputs |x|<~6 -> e<=2, no overflow
    u32 m3 = (r >> 20) & 7u;
    return (u8)(s | (u32)((e + 7) << 3) | m3);
}

// async global->LDS, 16B per lane; LDS dest = wave-uniform base + lane*16
__device__ __forceinline__ void ldg_to_lds16(const u8* g, u8* l) {
    __builtin_amdgcn_global_load_lds((__attribute__((address_space(1))) void*)(g),
                                     (__attribute__((address_space(3))) void*)(l),
                                     16, 0, 0);
}

// ---------------- init scratch state ----------------
__global__ void k_init(u32* rowMin, u64* rowBest, u32* counts, u32* candCnt,
                       float* lossPart) {
    int i = blockIdx.x * blockDim.x + threadIdx.x;
    if (i < M_ROWS) { rowMin[i] = 0xFFFFFFFFu; rowBest[i] = ~0ull; }
    if (i < N_CODES) counts[i] = 0u;
    if (i < NLOSSBIN) lossPart[i] = 0.0f;
    if (i == 0) *candCnt = 0u;
}

// ------- fp32 -> fp8 convert (k-PERMUTED row layout) + row squared norms -------
// Row layout (512 bytes): 8 BK-groups of 64B; each 16B block b of a group holds
// k_local = {8b..8b+7} U {32+8b..32+8b+7}. Both A and B use the same permutation,
// so MFMA dot products over the permuted order equal the true dot products.
// Lane l writes bytes [l*8, l*8+8): 8 consecutive source k's starting at
// k = (l>>3)*64 + (l&1)*32 + ((l&7)>>1)*8.
__global__ void k_convert8(const float* __restrict__ src, u8* __restrict__ dst,
                           float* __restrict__ nrm2, int nrows) {
    int row  = blockIdx.x * 4 + (threadIdx.x >> 6);
    int lane = threadIdx.x & 63;
    if (row >= nrows) return;
    int k0 = (lane >> 3) * 64 + (lane & 1) * 32 + ((lane & 7) >> 1) * 8;
    const float* p = src + (size_t)row * K_DIM + k0;
    float4 a = *(const float4*)p;
    float4 b = *(const float4*)(p + 4);
    u64 v = 0;
    v |= (u64)f2e4m3(a.x);       v |= (u64)f2e4m3(a.y) << 8;
    v |= (u64)f2e4m3(a.z) << 16; v |= (u64)f2e4m3(a.w) << 24;
    v |= (u64)f2e4m3(b.x) << 32; v |= (u64)f2e4m3(b.y) << 40;
    v |= (u64)f2e4m3(b.z) << 48; v |= (u64)f2e4m3(b.w) << 56;
    *(u64*)(dst + (size_t)row * K_DIM + lane * 8) = v;
    float ss = a.x*a.x + a.y*a.y + a.z*a.z + a.w*a.w
             + b.x*b.x + b.y*b.y + b.z*b.z + b.w*b.w;
    #pragma unroll
    for (int s = 32; s; s >>= 1) ss += __shfl_xor(ss, s);
    if (lane == 0) nrm2[row] = ss;
}

// ---------------- main fp8 GEMM + fused min/candidate epilogue ----------------
// s[m,n] = en2[n](fp32 exact) - 2 * fp8dot(z[m],e[n])  (row-wise argmin target)
// LDS tile rows = 64B (BK=64 fp8); XOR swizzle at 16B granularity:
//   block (R,b) stored at slot R*4 + (b ^ (R&3))
// -> one ds_read_b128 per fragment (covers BOTH k-halves via the permuted
//    layout); staging stays lane-linear for global_load_lds.
// Candidates aggregated in LDS slab, ONE global atomicAdd per block.
__global__ __launch_bounds__(256, 4)
void k_gemm(const u8* __restrict__ zb, const u8* __restrict__ eb,
            const float* __restrict__ en2, u32* __restrict__ rowMin,
            u32* __restrict__ candCnt, u64* __restrict__ cand) {
    __shared__ __align__(16) u8 As[BM * BK];   // 8 KB
    __shared__ __align__(16) u8 Bs[BN * BK];   // 8 KB
    __shared__ float en2s[BN];
    __shared__ u32 threshL[BM];
    __shared__ u64 candBuf[LCAP];
    __shared__ u32 ldsCnt, ldsBase;

    const int tid  = threadIdx.x;
    const int lane = tid & 63;
    const int wave = tid >> 6;
    const int rowTile = blockIdx.x * BM;
    const int nTile   = blockIdx.y * BN;
    const int wm = (wave >> 1) * 64;   // wave's row quadrant
    const int wn = (wave & 1) * 64;    // wave's col quadrant
    const int q  = lane >> 4;

    if (tid < BN) { en2s[tid] = en2[nTile + tid]; threshL[tid] = 0xFFFFFFFFu; }
    if (tid == 0) ldsCnt = 0u;

    // staging: 8 issues of 1KB each for A and for B per K-iter; wave w takes
    // issues i = w*2+t (t=0,1). Issue i covers tile rows [i*16, i*16+16);
    // lane l -> row i*16 + (l>>2), 16B-block g = (l&3) ^ ((l>>2)&3).
    const int srow = lane >> 2;
    const int sg   = (lane & 3) ^ ((lane >> 2) & 3);
    const u8* gA[2]; const u8* gB[2]; u8* lA[2]; u8* lB[2];
    #pragma unroll
    for (int t = 0; t < 2; t++) {
        int i = wave * 2 + t;
        gA[t] = zb + (size_t)(rowTile + i * 16 + srow) * K_DIM + sg * 16;
        gB[t] = eb + (size_t)(nTile   + i * 16 + srow) * K_DIM + sg * 16;
        lA[t] = As + i * 1024;
        lB[t] = Bs + i * 1024;
    }

    // fragment read byte offsets (one b128 covers both k-halves)
    int aoff[4], boff[4];
    #pragma unroll
    for (int t = 0; t < 4; t++) {
        int R  = wm + t * 16 + (lane & 15);
        aoff[t] = (R * 4 + (q ^ (R & 3))) * 16;
        int Rn = wn + t * 16 + (lane & 15);
        boff[t] = (Rn * 4 + (q ^ (Rn & 3))) * 16;
    }

    f32x4 acc[4][4] = {};

    for (int kk = 0; kk < KITERS; kk++) {
        const int ko = kk * BK;
        #pragma unroll
        for (int t = 0; t < 2; t++) {
            ldg_to_lds16(gA[t] + ko, lA[t]);
            ldg_to_lds16(gB[t] + ko, lB[t]);
        }
        __syncthreads();
        long2_t af[4], bf_[4];
        #pragma unroll
        for (int t = 0; t < 4; t++) {
            af[t]  = *(const long2_t*)(As + aoff[t]);
            bf_[t] = *(const long2_t*)(Bs + boff[t]);
        }
        #pragma unroll
        for (int i = 0; i < 4; i++)
            #pragma unroll
            for (int j = 0; j < 4; j++)
                acc[i][j] = __builtin_amdgcn_mfma_f32_16x16x32_fp8_fp8(af[i][0], bf_[j][0], acc[i][j], 0, 0, 0);
        #pragma unroll
        for (int i = 0; i < 4; i++)
            #pragma unroll
            for (int j = 0; j < 4; j++)
                acc[i][j] = __builtin_amdgcn_mfma_f32_16x16x32_fp8_fp8(af[i][1], bf_[j][1], acc[i][j], 0, 0, 0);
        __syncthreads();
    }

    // ---- epilogue: s = en2 - 2*C ; per-row tile min ; candidate capture ----
    float e2v[4];
    #pragma unroll
    for (int j = 0; j < 4; j++) e2v[j] = en2s[wn + j * 16 + (lane & 15)];
    #pragma unroll
    for (int i = 0; i < 4; i++)
        #pragma unroll
        for (int j = 0; j < 4; j++)
            #pragma unroll
            for (int r = 0; r < 4; r++)
                acc[i][j][r] = e2v[j] - 2.0f * acc[i][j][r];

    float rm[4][4];
    #pragma unroll
    for (int i = 0; i < 4; i++)
        #pragma unroll
        for (int r = 0; r < 4; r++)
            rm[i][r] = fminf(fminf(acc[i][0][r], acc[i][1][r]),
                             fminf(acc[i][2][r], acc[i][3][r]));
    #pragma unroll
    for (int d = 1; d < 16; d <<= 1)
        #pragma unroll
        for (int i = 0; i < 4; i++)
            #pragma unroll
            for (int r = 0; r < 4; r++)
                rm[i][r] = fminf(rm[i][r], __shfl_xor(rm[i][r], d));

    if ((lane & 15) == 0) {
        #pragma unroll
        for (int i = 0; i < 4; i++)
            #pragma unroll
            for (int r = 0; r < 4; r++) {
                int lrow = wm + i * 16 + (lane >> 4) * 4 + r;
                u32 o = ford(rm[i][r]);
                atomicMin(&threshL[lrow], o);
                u32 old = atomicMin(&rowMin[rowTile + lrow], o);  // tightens via earlier tiles
                atomicMin(&threshL[lrow], old);
            }
    }
    __syncthreads();

    #pragma unroll
    for (int i = 0; i < 4; i++) {
        #pragma unroll
        for (int r = 0; r < 4; r++) {
            int lrow = wm + i * 16 + (lane >> 4) * 4 + r;
            float th = fordinv(threshL[lrow]) + TAU2;
            #pragma unroll
            for (int j = 0; j < 4; j++) {
                float sv = acc[i][j][r];
                if (sv <= th) {
                    u32 code = (u32)(nTile + wn + j * 16 + (lane & 15));
                    u64 pk = ((u64)ford(sv) << 32) |
                             (u64)(((u32)(rowTile + lrow) << 13) | code);
                    u32 idx = atomicAdd(&ldsCnt, 1u);       // LDS atomic: cheap
                    if (idx < LCAP) candBuf[idx] = pk;
                    else { u32 g = atomicAdd(candCnt, 1u);  // rare overflow path
                           if (g < CAND_CAP) cand[g] = pk; }
                }
            }
        }
    }
    __syncthreads();
    if (tid == 0) {
        u32 n = ldsCnt < LCAP ? ldsCnt : LCAP;
        ldsBase = atomicAdd(candCnt, n);                    // ONE global atomic per block
    }
    __syncthreads();
    u32 n = ldsCnt < LCAP ? ldsCnt : LCAP;
    for (u32 k2 = tid; k2 < n; k2 += 256) {
        u32 g = ldsBase + k2;
        if (g < CAND_CAP) cand[g] = candBuf[k2];
    }
}

// ---------------- fp32 exact refine of pruned candidates ----------------
__global__ void k_refine(const float* __restrict__ z, const float* __restrict__ emb,
                         const float* __restrict__ en2, const u32* __restrict__ candCnt,
                         const u64* __restrict__ cand, const u32* __restrict__ rowMin,
                         u64* __restrict__ rowBest) {
    u32 cnt = *candCnt; if (cnt > CAND_CAP) cnt = CAND_CAP;
    int gt = blockIdx.x * blockDim.x + threadIdx.x;
    u32 wid = (u32)(gt >> 6);
    int lane = gt & 63;
    u32 nw = (u32)((gridDim.x * blockDim.x) >> 6);
    for (u32 ci = wid; ci < cnt; ci += nw) {
        u64 pk = cand[ci];
        u32 rc = (u32)pk;
        u32 row = rc >> 13, code = rc & (N_CODES - 1);
        float ad = fordinv((u32)(pk >> 32));
        float gm = fordinv(rowMin[row]);
        if (ad > gm + TAU2) continue;   // pruned: can't be the true argmin
        const float4* zp = (const float4*)(z + (size_t)row * K_DIM) + lane * 2;
        const float4* ep = (const float4*)(emb + (size_t)code * K_DIM) + lane * 2;
        float4 a0 = zp[0], a1 = zp[1], b0 = ep[0], b1 = ep[1];
        float d = a0.x*b0.x + a0.y*b0.y + a0.z*b0.z + a0.w*b0.w
                + a1.x*b1.x + a1.y*b1.y + a1.z*b1.z + a1.w*b1.w;
        #pragma unroll
        for (int s = 32; s; s >>= 1) d += __shfl_xor(d, s);
        if (lane == 0) {
            float sv = en2[code] - 2.0f * d;
            u64 bk = ((u64)ford(sv) << 32) | (u64)code;
            atomicMin(rowBest + row, bk);
        }
    }
}

// ------- outputs: z_q gather, codes, counts, fused loss partials -------
__global__ void k_output(const u64* __restrict__ rowBest, const float* __restrict__ emb,
                         const float* __restrict__ zn2, float* __restrict__ out,
                         u32* __restrict__ counts, float* __restrict__ lossPart) {
    int row = blockIdx.x;
    u64 pk = rowBest[row];
    u32 code = (u32)(pk & 0xFFFFFFFFull);
    int t = threadIdx.x;  // 128 threads, 4 floats each
    float4 v = ((const float4*)(emb + (size_t)code * K_DIM))[t];
    ((float4*)(out + (size_t)row * K_DIM))[t] = v;
    if (t == 0) {
        out[OFF_CODES + row] = (float)code;
        atomicAdd(&counts[code], 1u);
        // ||z - e_c||^2 = zn2[row] + (en2[c] - 2 z.e_c) = zn2 + best s (fp32 exact)
        float d2 = zn2[row] + fordinv((u32)(pk >> 32));
        atomicAdd(&lossPart[row & (NLOSSBIN - 1)], d2);
    }
}

// ---------------- loss + perplexity ----------------
__global__ void k_final(const float* __restrict__ lossPart,
                        const u32* __restrict__ counts, float* __restrict__ out) {
    __shared__ float red[256];
    int t = threadIdx.x;
    float s1 = (t < NLOSSBIN) ? lossPart[t] : 0.0f;
    red[t] = s1; __syncthreads();
    for (int w = 128; w; w >>= 1) { if (t < w) red[t] += red[t + w]; __syncthreads(); }
    float lossSum = red[0];
    __syncthreads();
    float s2 = 0.f;
    for (int c = t; c < N_CODES; c += 256) {
        float p = (float)counts[c] * (1.0f / (float)M_ROWS);
        s2 += p * logf(p + 1e-10f);
    }
    red[t] = s2; __syncthreads();
    for (int w = 128; w; w >>= 1) { if (t < w) red[t] += red[t + w]; __syncthreads(); }
    if (t == 0) {
        out[OFF_LOSS] = 0.25f * lossSum / ((float)M_ROWS * (float)K_DIM);
        out[OFF_PERP] = expf(-red[0]);
    }
}

// ---------------- workspace layout (bytes) ----------------
#define WS_ZB8     ((size_t)0)                       // 32768*512 = 16777216
#define WS_EB8     ((size_t)16777216)                // 8192*512  = 4194304
#define WS_EN2     ((size_t)20971520)                // 8192*4
#define WS_ZN2     ((size_t)21004288)                // 32768*4
#define WS_ROWMIN  ((size_t)21135360)                // 32768*4
#define WS_ROWBEST ((size_t)21266432)                // 32768*8
#define WS_COUNTS  ((size_t)21528576)                // 8192*4
#define WS_CANDCNT ((size_t)21561344)                // 256
#define WS_LOSSP   ((size_t)21561600)                // 512
#define WS_CAND    ((size_t)21562112)                // 3M*8 = 25165824 -> total ~46.7MB

extern "C" void kernel_launch(void* const* d_in, const int* in_sizes, int n_in,
                              void* d_out, int out_size, void* d_ws, size_t ws_size,
                              hipStream_t stream) {
    const float* z   = (const float*)d_in[0];
    const float* emb = (const float*)d_in[1];
    float* out = (float*)d_out;
    char* ws = (char*)d_ws;

    u8*   zb      = (u8*)(ws + WS_ZB8);
    u8*   eb      = (u8*)(ws + WS_EB8);
    float* en2    = (float*)(ws + WS_EN2);
    float* zn2    = (float*)(ws + WS_ZN2);
    u32*  rowMin  = (u32*)(ws + WS_ROWMIN);
    u64*  rowBest = (u64*)(ws + WS_ROWBEST);
    u32*  counts  = (u32*)(ws + WS_COUNTS);
    u32*  candCnt = (u32*)(ws + WS_CANDCNT);
    float* lossP  = (float*)(ws + WS_LOSSP);
    u64*  cand    = (u64*)(ws + WS_CAND);

    k_init<<<dim3(M_ROWS / 256), dim3(256), 0, stream>>>(rowMin, rowBest, counts, candCnt, lossP);
    k_convert8<<<dim3(M_ROWS / 4), dim3(256), 0, stream>>>(z, zb, zn2, M_ROWS);
    k_convert8<<<dim3(N_CODES / 4), dim3(256), 0, stream>>>(emb, eb, en2, N_CODES);
    k_gemm<<<dim3(M_ROWS / BM, N_CODES / BN), dim3(256), 0, stream>>>(zb, eb, en2, rowMin, candCnt, cand);
    k_refine<<<dim3(1024), dim3(256), 0, stream>>>(z, emb, en2, candCnt, cand, rowMin, rowBest);
    k_output<<<dim3(M_ROWS), dim3(128), 0, stream>>>(rowBest, emb, zn2, out, counts, lossP);
    k_final<<<dim3(1), dim3(256), 0, stream>>>(lossP, counts, out);
}